// Round 4
// baseline (965.476 us; speedup 1.0000x reference)
//
#include <hip/hip_runtime.h>

typedef unsigned short ushort_t;
typedef unsigned int uint_t;
typedef __attribute__((ext_vector_type(8))) short bf16x8;   // 8 bf16 = 4 VGPR
typedef __attribute__((ext_vector_type(4))) float f32x4;    // MFMA C/D

#define B_SZ 2048
#define C_SZ 100
#define P_SZ 128
#define D_SZ 192
#define CH   32     // prompts per chunk
#define NCH  4      // chunks (P_SZ / CH)

#define MFMA16 __builtin_amdgcn_mfma_f32_16x16x32_bf16

// ---- batch-independent tables as device globals (no workspace dependency) ----
__device__ ushort_t g_colb_hi[P_SZ * D_SZ];   // LN(emb_column) hi, rows [100,128) zero
__device__ ushort_t g_colb_lo[P_SZ * D_SZ];   // LN(emb_column) lo
__device__ float    g_cp[P_SZ * D_SZ];        // LN(emb_prompt)@W1 + b_imp + emb_prompt
__device__ ushort_t g_w2t_hi[D_SZ * D_SZ];    // W2^T hi: [d][e], e(K)-contiguous
__device__ ushort_t g_w2t_lo[D_SZ * D_SZ];    // W2^T lo

__device__ __forceinline__ float b2f(ushort_t u) {
    union { uint_t i; float f; } v; v.i = ((uint_t)u) << 16; return v.f;
}
__device__ __forceinline__ ushort_t f2b(float f) {
    uint_t x = __float_as_uint(f);
    uint_t r = x + 0x7fffu + ((x >> 16) & 1u);  // RNE
    return (ushort_t)(r >> 16);
}
__device__ __forceinline__ uint_t packhl(float f) {   // (hi<<16)|lo split-bf16
    const ushort_t h = f2b(f);
    const ushort_t lo = f2b(f - b2f(h));
    return ((uint_t)h << 16) | (uint_t)lo;
}

// ---- full 3-bit XOR quad swizzles (16B-quad granularity) ----
__device__ __forceinline__ int xet_off(int d, int c) {   // ushort idx, row=128 us
    return d * 128 + ((((c >> 3) ^ (d & 7)) << 3) | (c & 7));
}
__device__ __forceinline__ int y_off(int r, int col) {   // u32 idx, row=192 u32
    return r * 192 + ((((col >> 2) ^ (r & 7)) << 2) | (col & 3));
}

// ---------------- K0: batch-independent precompute (unchanged, verified) ----------------
__global__ __launch_bounds__(192) void precompute(
    const float* __restrict__ emb_column, const float* __restrict__ emb_prompt,
    const float* __restrict__ ln_col_w, const float* __restrict__ ln_col_b,
    const float* __restrict__ ln_prompt_w, const float* __restrict__ ln_prompt_b,
    const float* __restrict__ W_imp, const float* __restrict__ b_imp)
{
    const int r = blockIdx.x;
    const int t = threadIdx.x;            // 0..191
    const int wid = t >> 6, lane = t & 63;
    __shared__ float redS[3], redQ[3];
    __shared__ float rowv[D_SZ];

    if (r < C_SZ) {
        float v = emb_column[r * D_SZ + t];
        float s = v, q = v * v;
        #pragma unroll
        for (int o = 1; o < 64; o <<= 1) { s += __shfl_xor(s, o); q += __shfl_xor(q, o); }
        if (lane == 0) { redS[wid] = s; redQ[wid] = q; }
        __syncthreads();
        s = redS[0] + redS[1] + redS[2];
        q = redQ[0] + redQ[1] + redQ[2];
        float m = s * (1.f / D_SZ);
        float var = fmaxf(q * (1.f / D_SZ) - m * m, 0.f);
        float rs = rsqrtf(var + 1e-5f);
        float o = (v - m) * rs * ln_col_w[t] + ln_col_b[t];
        ushort_t h = f2b(o);
        g_colb_hi[r * D_SZ + t] = h;
        g_colb_lo[r * D_SZ + t] = f2b(o - b2f(h));
    } else if (r < P_SZ) {
        g_colb_hi[r * D_SZ + t] = 0;
        g_colb_lo[r * D_SZ + t] = 0;
    } else if (r < 2 * P_SZ) {
        const int p = r - P_SZ;
        float v = emb_prompt[p * D_SZ + t];
        float s = v, q = v * v;
        #pragma unroll
        for (int o = 1; o < 64; o <<= 1) { s += __shfl_xor(s, o); q += __shfl_xor(q, o); }
        if (lane == 0) { redS[wid] = s; redQ[wid] = q; }
        __syncthreads();
        s = redS[0] + redS[1] + redS[2];
        q = redQ[0] + redQ[1] + redQ[2];
        float m = s * (1.f / D_SZ);
        float var = fmaxf(q * (1.f / D_SZ) - m * m, 0.f);
        float rs = rsqrtf(var + 1e-5f);
        rowv[t] = (v - m) * rs * ln_prompt_w[t] + ln_prompt_b[t];
        __syncthreads();
        float a0 = 0.f, a1 = 0.f, a2 = 0.f, a3 = 0.f;
        for (int e = 0; e < D_SZ; e += 4) {
            a0 = fmaf(rowv[e + 0], W_imp[(e + 0) * D_SZ + t], a0);
            a1 = fmaf(rowv[e + 1], W_imp[(e + 1) * D_SZ + t], a1);
            a2 = fmaf(rowv[e + 2], W_imp[(e + 2) * D_SZ + t], a2);
            a3 = fmaf(rowv[e + 3], W_imp[(e + 3) * D_SZ + t], a3);
        }
        g_cp[p * D_SZ + t] = b_imp[t] + v + ((a0 + a1) + (a2 + a3));
    } else {
        const int d0 = (r - 2 * P_SZ) * 4;
        const float4 wv = *(const float4*)(W_imp + (D_SZ + t) * D_SZ + d0);
        const float vv[4] = {wv.x, wv.y, wv.z, wv.w};
        #pragma unroll
        for (int j = 0; j < 4; ++j) {
            const ushort_t h = f2b(vv[j]);
            g_w2t_hi[(d0 + j) * D_SZ + t] = h;
            g_w2t_lo[(d0 + j) * D_SZ + t] = f2b(vv[j] - b2f(h));
        }
    }
}

// ---------------- K1: per-batch fused, MFMA + pipelined loads ----------------
// 512 threads = 8 waves, one block per batch; P in 4 chunks of 32.
// LDS ~74 KB -> 2 blocks/CU. Plain launch_bounds: compiler targets <=128 VGPR.
__global__ __launch_bounds__(512) void fused(
    const float* __restrict__ x, const float* __restrict__ prev,
    const float* __restrict__ wfe, const float* __restrict__ bfe,
    const float* __restrict__ lnw, const float* __restrict__ lnb,
    const float* __restrict__ wexp, const float* __restrict__ bexp,
    float* __restrict__ out)
{
    __shared__ __align__(16) ushort_t xeT[D_SZ * 128];   // 49152 B: x_emb^T [d][c] swizzled
    __shared__ __align__(16) uint_t   ylds[CH * D_SZ];   // 24576 B: prev-packed / y-packed
    __shared__ __align__(16) float    psum[CH * 4];      // 512 B: per-row partial softmax sums
    ushort_t* maskb = (ushort_t*)ylds;                    // overlay [32][128] bf16 (8192 B)

    const int b    = blockIdx.x;
    const int tid  = threadIdx.x;
    const int w    = tid >> 6;
    const int l    = tid & 63;
    const int l15  = l & 15;
    const int lg   = l >> 4;          // 0..3 row-quad group
    const int koff = lg * 8;
    const size_t bP = (size_t)b * P_SZ;
    const f32x4 fzero = {0.f, 0.f, 0.f, 0.f};

    // ---- prologue: issue prev(chunk 0) loads (hide under stage 0) ----
    float4 pf0, pf1, pf2;
    {
        const float* pc = prev + bP * D_SZ;
        pf0 = *(const float4*)(pc + (tid)         * 4);
        pf1 = *(const float4*)(pc + (tid + 512)   * 4);
        pf2 = *(const float4*)(pc + (tid + 1024)  * 4);
    }

    // ---- stage 0: x_emb^T = LN(relu(x*wfe+bfe))^T -> xeT[d][c] (bf16, swizzled) ----
    {
        const float lw0 = lnw[l],       lb0 = lnb[l];
        const float lw1 = lnw[l + 64],  lb1 = lnb[l + 64];
        const float lw2 = lnw[l + 128], lb2 = lnb[l + 128];
        for (int c = w; c < C_SZ; c += 8) {           // wave-per-column
            const float xv = x[b * C_SZ + c];
            const float* wr = wfe + c * D_SZ;
            const float* br = bfe + c * D_SZ;
            float v0 = fmaxf(fmaf(xv, wr[l],       br[l]),       0.f);
            float v1 = fmaxf(fmaf(xv, wr[l + 64],  br[l + 64]),  0.f);
            float v2 = fmaxf(fmaf(xv, wr[l + 128], br[l + 128]), 0.f);
            float s = v0 + v1 + v2;
            float q = v0 * v0 + v1 * v1 + v2 * v2;
            #pragma unroll
            for (int o = 1; o < 64; o <<= 1) { s += __shfl_xor(s, o); q += __shfl_xor(q, o); }
            const float m   = s * (1.f / D_SZ);
            const float var = fmaxf(q * (1.f / D_SZ) - m * m, 0.f);
            const float rs  = rsqrtf(var + 1e-5f);
            xeT[xet_off(l,       c)] = f2b((v0 - m) * rs * lw0 + lb0);
            xeT[xet_off(l + 64,  c)] = f2b((v1 - m) * rs * lw1 + lb1);
            xeT[xet_off(l + 128, c)] = f2b((v2 - m) * rs * lw2 + lb2);
        }
        for (int idx = tid; idx < D_SZ * 28; idx += 512)   // zero K-pad c in [100,128)
            xeT[xet_off(idx / 28, C_SZ + (idx % 28))] = 0;
    }

    // ---- consume prologue prefetch: pack + swizzled ds_write of prev(0) ----
    {
        uint4 u;
        int idx, row, q;
        u.x = packhl(pf0.x); u.y = packhl(pf0.y); u.z = packhl(pf0.z); u.w = packhl(pf0.w);
        idx = tid;        row = idx / 48; q = idx % 48;
        *(uint4*)(ylds + row * 192 + ((q ^ (row & 7)) << 2)) = u;
        u.x = packhl(pf1.x); u.y = packhl(pf1.y); u.z = packhl(pf1.z); u.w = packhl(pf1.w);
        idx = tid + 512;  row = idx / 48; q = idx % 48;
        *(uint4*)(ylds + row * 192 + ((q ^ (row & 7)) << 2)) = u;
        u.x = packhl(pf2.x); u.y = packhl(pf2.y); u.z = packhl(pf2.z); u.w = packhl(pf2.w);
        idx = tid + 1024; row = idx / 48; q = idx % 48;
        *(uint4*)(ylds + row * 192 + ((q ^ (row & 7)) << 2)) = u;
    }
    __syncthreads();   // B1: xeT + prev(0) ready

    for (int chunk = 0; chunk < NCH; ++chunk) {
        const int pbase = chunk * CH;

        // ---- G1: y[32][192] = prev @ W2 (+cp), hi/lo split, 2-deep pipelined ----
        {
            const int wm = w >> 2, wn = w & 3;    // 2M x 4N: wave tile 16 x 48
            f32x4 acc[3] = {fzero, fzero, fzero};
            const int arow = 16 * wm + l15;
            const int r7 = arow & 7;
            const uint_t* abase = ylds + arow * 192;
            bf16x8 bh[2][3], bl[2][3];
            uint4 au[2][2];
            {   // preload kt = 0
                const int q0 = lg * 2;
                au[0][0] = *(const uint4*)(abase + ((q0 ^ r7) << 2));
                au[0][1] = *(const uint4*)(abase + (((q0 + 1) ^ r7) << 2));
                #pragma unroll
                for (int nt = 0; nt < 3; ++nt) {
                    const int drow = 48 * wn + 16 * nt + l15;
                    bh[0][nt] = *(const bf16x8*)(g_w2t_hi + drow * D_SZ + koff);
                    bl[0][nt] = *(const bf16x8*)(g_w2t_lo + drow * D_SZ + koff);
                }
            }
            #pragma unroll
            for (int kt = 0; kt < 6; ++kt) {
                const int cur = kt & 1, nxt = cur ^ 1;
                if (kt < 5) {   // prefetch kt+1 (A from LDS, B from L2)
                    const int q1 = (kt + 1) * 8 + lg * 2;
                    au[nxt][0] = *(const uint4*)(abase + ((q1 ^ r7) << 2));
                    au[nxt][1] = *(const uint4*)(abase + (((q1 + 1) ^ r7) << 2));
                    const int e1 = (kt + 1) * 32 + koff;
                    #pragma unroll
                    for (int nt = 0; nt < 3; ++nt) {
                        const int drow = 48 * wn + 16 * nt + l15;
                        bh[nxt][nt] = *(const bf16x8*)(g_w2t_hi + drow * D_SZ + e1);
                        bl[nxt][nt] = *(const bf16x8*)(g_w2t_lo + drow * D_SZ + e1);
                    }
                }
                const uint_t uu[8] = {au[cur][0].x, au[cur][0].y, au[cur][0].z, au[cur][0].w,
                                      au[cur][1].x, au[cur][1].y, au[cur][1].z, au[cur][1].w};
                bf16x8 ah, al;
                #pragma unroll
                for (int j = 0; j < 8; ++j) {
                    ah[j] = (short)(uu[j] >> 16);
                    al[j] = (short)(uu[j] & 0xffffu);
                }
                #pragma unroll
                for (int nt = 0; nt < 3; ++nt) {
                    acc[nt] = MFMA16(ah, bh[cur][nt], acc[nt], 0, 0, 0);
                    acc[nt] = MFMA16(al, bh[cur][nt], acc[nt], 0, 0, 0);
                    acc[nt] = MFMA16(ah, bl[cur][nt], acc[nt], 0, 0, 0);
                }
            }
            __syncthreads();   // B2: all prev reads done before y overwrite
            const int pr0 = 16 * wm + 4 * lg;
            #pragma unroll
            for (int nt = 0; nt < 3; ++nt) {
                const int d = 48 * wn + 16 * nt + l15;
                #pragma unroll
                for (int r = 0; r < 4; ++r) {
                    const int pl = pr0 + r;
                    const float y = acc[nt][r] + g_cp[(pbase + pl) * D_SZ + d];
                    ylds[y_off(pl, d)] = packhl(y);
                }
            }
        }
        __syncthreads();   // B3: y ready

        // ---- issue prev(chunk+1) prefetch (hides under G2+softmax+G3) ----
        float4 pf0n, pf1n, pf2n;
        if (chunk + 1 < NCH) {
            const float* pc = prev + (bP + (size_t)(chunk + 1) * CH) * D_SZ;
            pf0n = *(const float4*)(pc + (tid)        * 4);
            pf1n = *(const float4*)(pc + (tid + 512)  * 4);
            pf2n = *(const float4*)(pc + (tid + 1024) * 4);
        }

        // ---- G2: s[32][128] = y @ col^T, hi/lo split, 2-deep pipelined ----
        f32x4 sacc[2] = {fzero, fzero};
        const int wm2 = w >> 2, wn2 = w & 3;   // 2M x 4N: wave tile 16 x 32
        {
            const int prow = 16 * wm2 + l15;
            const int r7 = prow & 7;
            const uint_t* ybase = ylds + prow * 192;
            bf16x8 bh[2][2], bl[2][2];
            uint4 au[2][2];
            {   // preload kt = 0
                const int q0 = lg * 2;
                au[0][0] = *(const uint4*)(ybase + ((q0 ^ r7) << 2));
                au[0][1] = *(const uint4*)(ybase + (((q0 + 1) ^ r7) << 2));
                #pragma unroll
                for (int nt = 0; nt < 2; ++nt) {
                    const int crow = 32 * wn2 + 16 * nt + l15;
                    bh[0][nt] = *(const bf16x8*)(g_colb_hi + crow * D_SZ + koff);
                    bl[0][nt] = *(const bf16x8*)(g_colb_lo + crow * D_SZ + koff);
                }
            }
            #pragma unroll
            for (int kt = 0; kt < 6; ++kt) {
                const int cur = kt & 1, nxt = cur ^ 1;
                if (kt < 5) {
                    const int q1 = (kt + 1) * 8 + lg * 2;
                    au[nxt][0] = *(const uint4*)(ybase + ((q1 ^ r7) << 2));
                    au[nxt][1] = *(const uint4*)(ybase + (((q1 + 1) ^ r7) << 2));
                    const int e1 = (kt + 1) * 32 + koff;
                    #pragma unroll
                    for (int nt = 0; nt < 2; ++nt) {
                        const int crow = 32 * wn2 + 16 * nt + l15;
                        bh[nxt][nt] = *(const bf16x8*)(g_colb_hi + crow * D_SZ + e1);
                        bl[nxt][nt] = *(const bf16x8*)(g_colb_lo + crow * D_SZ + e1);
                    }
                }
                const uint_t uu[8] = {au[cur][0].x, au[cur][0].y, au[cur][0].z, au[cur][0].w,
                                      au[cur][1].x, au[cur][1].y, au[cur][1].z, au[cur][1].w};
                bf16x8 ah, al;
                #pragma unroll
                for (int j = 0; j < 8; ++j) {
                    ah[j] = (short)(uu[j] >> 16);
                    al[j] = (short)(uu[j] & 0xffffu);
                }
                #pragma unroll
                for (int nt = 0; nt < 2; ++nt) {
                    sacc[nt] = MFMA16(ah, bh[cur][nt], sacc[nt], 0, 0, 0);
                    sacc[nt] = MFMA16(al, bh[cur][nt], sacc[nt], 0, 0, 0);
                    sacc[nt] = MFMA16(ah, bl[cur][nt], sacc[nt], 0, 0, 0);
                }
            }
        }

        // ---- in-register max-free softmax: e, per-row sums, psum combine ----
        float e[2][4];
        {
            #pragma unroll
            for (int nt = 0; nt < 2; ++nt) {
                const int col = 32 * wn2 + 16 * nt + l15;
                #pragma unroll
                for (int r = 0; r < 4; ++r)
                    e[nt][r] = (col < C_SZ) ? __expf(sacc[nt][r]) : 0.f;
            }
            #pragma unroll
            for (int r = 0; r < 4; ++r) {
                float rs = e[0][r] + e[1][r];
                rs += __shfl_xor(rs, 1); rs += __shfl_xor(rs, 2);
                rs += __shfl_xor(rs, 4); rs += __shfl_xor(rs, 8);
                if (l15 == 0) psum[(16 * wm2 + 4 * lg + r) * 4 + wn2] = rs;
            }
        }
        __syncthreads();   // B4: psum ready; all y reads done (maskb overlay safe)
        {
            #pragma unroll
            for (int r = 0; r < 4; ++r) {
                const int row = 16 * wm2 + 4 * lg + r;
                const float4 ps = *(const float4*)(psum + row * 4);
                const float inv = 1.f / (ps.x + ps.y + ps.z + ps.w);
                #pragma unroll
                for (int nt = 0; nt < 2; ++nt) {
                    const int col = 32 * wn2 + 16 * nt + l15;
                    maskb[row * 128 + ((((col >> 3) ^ (row & 7)) << 3) | (col & 7))]
                        = f2b(e[nt][r] * inv);
                }
            }
        }
        __syncthreads();   // B5: maskb ready

        // ---- G3: agg[32][192] = mask @ x_emb (K=128 padded), + epilogue store ----
        {
            const int wm3 = w >> 2, wn3 = w & 3;   // 2M x 4N: wave tile 16 x 48
            f32x4 acc[3] = {fzero, fzero, fzero};
            const int arow = 16 * wm3 + l15;
            #pragma unroll
            for (int kt = 0; kt < 4; ++kt) {
                const int c0 = kt * 32 + koff;
                const bf16x8 a = *(const bf16x8*)(maskb + arow * 128 +
                                                  (((c0 >> 3) ^ (arow & 7)) << 3));
                #pragma unroll
                for (int nt = 0; nt < 3; ++nt) {
                    const int d = 48 * wn3 + 16 * nt + l15;
                    const bf16x8 bx = *(const bf16x8*)(xeT + d * 128 +
                                                       (((c0 >> 3) ^ (d & 7)) << 3));
                    acc[nt] = MFMA16(a, bx, acc[nt], 0, 0, 0);
                }
            }
            const int pr0 = pbase + 16 * wm3 + 4 * lg;
            #pragma unroll
            for (int r = 0; r < 4; ++r) {
                const int p = pr0 + r;
                const float sc = 1.f + wexp[p];
                const float bi = bexp[p];
                float* orow = out + (bP + p) * D_SZ;
                #pragma unroll
                for (int nt = 0; nt < 3; ++nt) {
                    const int d = 48 * wn3 + 16 * nt + l15;
                    orow[d] = fmaf(acc[nt][r], sc, bi);
                }
            }
        }
        __syncthreads();   // B6: maskb reads done -> ylds reusable

        // ---- consume prefetch: pack + ds_write prev(chunk+1) ----
        if (chunk + 1 < NCH) {
            uint4 u;
            int idx, row, q;
            u.x = packhl(pf0n.x); u.y = packhl(pf0n.y); u.z = packhl(pf0n.z); u.w = packhl(pf0n.w);
            idx = tid;        row = idx / 48; q = idx % 48;
            *(uint4*)(ylds + row * 192 + ((q ^ (row & 7)) << 2)) = u;
            u.x = packhl(pf1n.x); u.y = packhl(pf1n.y); u.z = packhl(pf1n.z); u.w = packhl(pf1n.w);
            idx = tid + 512;  row = idx / 48; q = idx % 48;
            *(uint4*)(ylds + row * 192 + ((q ^ (row & 7)) << 2)) = u;
            u.x = packhl(pf2n.x); u.y = packhl(pf2n.y); u.z = packhl(pf2n.z); u.w = packhl(pf2n.w);
            idx = tid + 1024; row = idx / 48; q = idx % 48;
            *(uint4*)(ylds + row * 192 + ((q ^ (row & 7)) << 2)) = u;
            __syncthreads();   // B1': prev(chunk+1) ready
        }
    }
}

extern "C" void kernel_launch(void* const* d_in, const int* in_sizes, int n_in,
                              void* d_out, int out_size, void* d_ws, size_t ws_size,
                              hipStream_t stream) {
    const float* x           = (const float*)d_in[0];
    const float* prev        = (const float*)d_in[1];
    const float* wfe         = (const float*)d_in[2];
    const float* bfe         = (const float*)d_in[3];
    const float* ln_emb_w    = (const float*)d_in[4];
    const float* ln_emb_b    = (const float*)d_in[5];
    const float* ln_col_w    = (const float*)d_in[6];
    const float* ln_col_b    = (const float*)d_in[7];
    const float* ln_prompt_w = (const float*)d_in[8];
    const float* ln_prompt_b = (const float*)d_in[9];
    const float* W_imp       = (const float*)d_in[10];
    const float* b_imp       = (const float*)d_in[11];
    const float* emb_column  = (const float*)d_in[12];
    const float* emb_prompt  = (const float*)d_in[13];
    const float* wexp        = (const float*)d_in[14];
    const float* bexp        = (const float*)d_in[15];
    float* out = (float*)d_out;
    (void)d_ws; (void)ws_size;

    precompute<<<2 * P_SZ + 48, 192, 0, stream>>>(emb_column, emb_prompt,
        ln_col_w, ln_col_b, ln_prompt_w, ln_prompt_b, W_imp, b_imp);
    fused<<<B_SZ, 512, 0, stream>>>(x, prev, wfe, bfe, ln_emb_w, ln_emb_b,
        wexp, bexp, out);
}

// Round 5
// 536.668 us; speedup vs baseline: 1.7990x; 1.7990x over previous
//
#include <hip/hip_runtime.h>

typedef unsigned short ushort_t;
typedef unsigned int uint_t;
typedef __attribute__((ext_vector_type(8))) short bf16x8;   // 8 bf16 = 4 VGPR
typedef __attribute__((ext_vector_type(4))) float f32x4;    // MFMA C/D

#define B_SZ 2048
#define C_SZ 100
#define P_SZ 128
#define D_SZ 192
#define CH   32     // prompts per chunk
#define NCH  4      // chunks (P_SZ / CH)

#define MFMA16 __builtin_amdgcn_mfma_f32_16x16x32_bf16

// Only cross-kernel intermediate kept as device global (98 KB).
__device__ float g_cp[P_SZ * D_SZ];   // LN(emb_prompt)@W1 + b_imp + emb_prompt

__device__ __forceinline__ float b2f(ushort_t u) {
    union { uint_t i; float f; } v; v.i = ((uint_t)u) << 16; return v.f;
}
__device__ __forceinline__ ushort_t f2b(float f) {
    uint_t x = __float_as_uint(f);
    uint_t r = x + 0x7fffu + ((x >> 16) & 1u);  // RNE
    return (ushort_t)(r >> 16);
}
__device__ __forceinline__ uint_t packhl(float f) {   // (hi<<16)|lo split-bf16
    const ushort_t h = f2b(f);
    const ushort_t lo = f2b(f - b2f(h));
    return ((uint_t)h << 16) | (uint_t)lo;
}

// xeT swizzle: row = d (128 ushorts), quad index XORed with d&7
__device__ __forceinline__ int xet_off(int d, int c) {
    return d * 128 + ((((c >> 3) ^ (d & 7)) << 3) | (c & 7));
}

// ---------------- K0a: colLN -> W2C rows; cp ----------------
// blocks [0,100)   : wc_hi/lo[c][e] = split( sum_d W2[e][d] * LN(emb_column[c])[d] )
// blocks [100,128) : wc rows -> 0 (finite pad for B-fragments)
// blocks [128,256) : g_cp[p][:] = LN(emb_prompt[p]) @ W1 + b_imp + emb_prompt[p]
__global__ __launch_bounds__(192) void precompute1(
    const float* __restrict__ emb_column, const float* __restrict__ emb_prompt,
    const float* __restrict__ ln_col_w, const float* __restrict__ ln_col_b,
    const float* __restrict__ ln_prompt_w, const float* __restrict__ ln_prompt_b,
    const float* __restrict__ W_imp, const float* __restrict__ b_imp,
    ushort_t* __restrict__ wc_hi, ushort_t* __restrict__ wc_lo)
{
    const int r = blockIdx.x;
    const int t = threadIdx.x;            // 0..191
    const int wid = t >> 6, lane = t & 63;
    __shared__ float redS[3], redQ[3];
    __shared__ float rowv[D_SZ];

    if (r < C_SZ) {
        float v = emb_column[r * D_SZ + t];
        float s = v, q = v * v;
        #pragma unroll
        for (int o = 1; o < 64; o <<= 1) { s += __shfl_xor(s, o); q += __shfl_xor(q, o); }
        if (lane == 0) { redS[wid] = s; redQ[wid] = q; }
        __syncthreads();
        s = redS[0] + redS[1] + redS[2];
        q = redQ[0] + redQ[1] + redQ[2];
        float m = s * (1.f / D_SZ);
        float var = fmaxf(q * (1.f / D_SZ) - m * m, 0.f);
        float rs = rsqrtf(var + 1e-5f);
        rowv[t] = (v - m) * rs * ln_col_w[t] + ln_col_b[t];
        __syncthreads();
        // W2C[r][e=t] = sum_d W2[t][d] * colLN[r][d]
        const float* wrow = W_imp + (size_t)(D_SZ + t) * D_SZ;
        float a0 = 0.f, a1 = 0.f, a2 = 0.f, a3 = 0.f;
        for (int d = 0; d < D_SZ; d += 4) {
            a0 = fmaf(wrow[d + 0], rowv[d + 0], a0);
            a1 = fmaf(wrow[d + 1], rowv[d + 1], a1);
            a2 = fmaf(wrow[d + 2], rowv[d + 2], a2);
            a3 = fmaf(wrow[d + 3], rowv[d + 3], a3);
        }
        const float acc = (a0 + a1) + (a2 + a3);
        const ushort_t h = f2b(acc);
        wc_hi[r * D_SZ + t] = h;
        wc_lo[r * D_SZ + t] = f2b(acc - b2f(h));
    } else if (r < P_SZ) {
        wc_hi[r * D_SZ + t] = 0;
        wc_lo[r * D_SZ + t] = 0;
    } else {
        const int p = r - P_SZ;
        float v = emb_prompt[p * D_SZ + t];
        float s = v, q = v * v;
        #pragma unroll
        for (int o = 1; o < 64; o <<= 1) { s += __shfl_xor(s, o); q += __shfl_xor(q, o); }
        if (lane == 0) { redS[wid] = s; redQ[wid] = q; }
        __syncthreads();
        s = redS[0] + redS[1] + redS[2];
        q = redQ[0] + redQ[1] + redQ[2];
        float m = s * (1.f / D_SZ);
        float var = fmaxf(q * (1.f / D_SZ) - m * m, 0.f);
        float rs = rsqrtf(var + 1e-5f);
        rowv[t] = (v - m) * rs * ln_prompt_w[t] + ln_prompt_b[t];
        __syncthreads();
        float a0 = 0.f, a1 = 0.f, a2 = 0.f, a3 = 0.f;
        for (int e = 0; e < D_SZ; e += 4) {
            a0 = fmaf(rowv[e + 0], W_imp[(e + 0) * D_SZ + t], a0);
            a1 = fmaf(rowv[e + 1], W_imp[(e + 1) * D_SZ + t], a1);
            a2 = fmaf(rowv[e + 2], W_imp[(e + 2) * D_SZ + t], a2);
            a3 = fmaf(rowv[e + 3], W_imp[(e + 3) * D_SZ + t], a3);
        }
        g_cp[p * D_SZ + t] = b_imp[t] + v + ((a0 + a1) + (a2 + a3));
    }
}

// ---------------- K0b: cpc[p][c] = cp[p] . LN(emb_column[c]) ----------------
// grid 128 blocks x 128 threads (t = c, pad c>=100 -> 0)
__global__ __launch_bounds__(128) void precompute2(
    const float* __restrict__ emb_column,
    const float* __restrict__ ln_col_w, const float* __restrict__ ln_col_b,
    float* __restrict__ cpc)
{
    const int p = blockIdx.x, t = threadIdx.x;
    __shared__ float wcp[D_SZ], bcp[D_SZ];
    for (int i = t; i < D_SZ; i += 128) {
        const float cv = g_cp[p * D_SZ + i];
        wcp[i] = ln_col_w[i] * cv;
        bcp[i] = ln_col_b[i] * cv;
    }
    __syncthreads();
    if (t < C_SZ) {
        const float* er = emb_column + (size_t)t * D_SZ;
        float sv = 0.f, sq = 0.f, s1 = 0.f, sw = 0.f, sb = 0.f;
        for (int d = 0; d < D_SZ; ++d) {
            const float v = er[d];
            sv += v; sq += v * v;
            s1 = fmaf(v, wcp[d], s1);
            sw += wcp[d]; sb += bcp[d];
        }
        const float m = sv * (1.f / D_SZ);
        const float var = fmaxf(sq * (1.f / D_SZ) - m * m, 0.f);
        const float rs = rsqrtf(var + 1e-5f);
        // sum_d ((v-m)*rs*w + b)*cp = rs*(s1 - m*sw) + sb
        cpc[p * 128 + t] = rs * (s1 - m * sw) + sb;
    } else {
        cpc[p * 128 + t] = 0.f;
    }
}

// ---------------- K1: per-batch fused ----------------
// 512 threads = 8 waves, one block per batch; P in 4 chunks of 32.
// LDS = 73728 B exactly -> 2 blocks/CU (usable LDS/CU measured = 144 KB).
__global__ __launch_bounds__(512) void fused(
    const float* __restrict__ x, const float* __restrict__ prev,
    const float* __restrict__ wfe, const float* __restrict__ bfe,
    const float* __restrict__ lnw, const float* __restrict__ lnb,
    const float* __restrict__ wexp, const float* __restrict__ bexp,
    const ushort_t* __restrict__ wc_hi, const ushort_t* __restrict__ wc_lo,
    const float* __restrict__ cpc,
    float* __restrict__ out)
{
    __shared__ __align__(16) ushort_t xeT[D_SZ * 128];   // 49152 B (pad cols host psum)
    __shared__ __align__(16) uint_t   ylds[CH * D_SZ];   // 24576 B: packed prev chunk
    ushort_t* maskb = (ushort_t*)ylds;                    // overlay [32][128] bf16 (8192 B)
    uint_t*   xeT32 = (uint_t*)xeT;

    const int b    = blockIdx.x;
    const int tid  = threadIdx.x;
    const int w    = tid >> 6;
    const int l    = tid & 63;
    const int l15  = l & 15;
    const int lg   = l >> 4;          // 0..3
    const int koff = lg * 8;
    const int wm   = w >> 2;          // 0..1 : 16-row group
    const int wn   = w & 3;           // 0..3 : col group
    const size_t bP = (size_t)b * P_SZ;
    const f32x4 fzero = {0.f, 0.f, 0.f, 0.f};

    // ---- prologue: issue prev(chunk 0) loads (hide under stage 0) ----
    float4 pf0, pf1, pf2;
    {
        const float* pc = prev + bP * D_SZ;
        pf0 = *(const float4*)(pc + (tid)        * 4);
        pf1 = *(const float4*)(pc + (tid + 512)  * 4);
        pf2 = *(const float4*)(pc + (tid + 1024) * 4);
    }

    // ---- stage 0: x_emb^T = LN(relu(x*wfe+bfe))^T -> xeT[d][c] (bf16, swizzled) ----
    {
        const float lw0 = lnw[l],       lb0 = lnb[l];
        const float lw1 = lnw[l + 64],  lb1 = lnb[l + 64];
        const float lw2 = lnw[l + 128], lb2 = lnb[l + 128];
        for (int c = w; c < C_SZ; c += 8) {           // wave-per-column
            const float xv = x[b * C_SZ + c];
            const float* wr = wfe + c * D_SZ;
            const float* br = bfe + c * D_SZ;
            float v0 = fmaxf(fmaf(xv, wr[l],       br[l]),       0.f);
            float v1 = fmaxf(fmaf(xv, wr[l + 64],  br[l + 64]),  0.f);
            float v2 = fmaxf(fmaf(xv, wr[l + 128], br[l + 128]), 0.f);
            float s = v0 + v1 + v2;
            float q = v0 * v0 + v1 * v1 + v2 * v2;
            #pragma unroll
            for (int o = 1; o < 64; o <<= 1) { s += __shfl_xor(s, o); q += __shfl_xor(q, o); }
            const float m   = s * (1.f / D_SZ);
            const float var = fmaxf(q * (1.f / D_SZ) - m * m, 0.f);
            const float rs  = rsqrtf(var + 1e-5f);
            xeT[xet_off(l,       c)] = f2b((v0 - m) * rs * lw0 + lb0);
            xeT[xet_off(l + 64,  c)] = f2b((v1 - m) * rs * lw1 + lb1);
            xeT[xet_off(l + 128, c)] = f2b((v2 - m) * rs * lw2 + lb2);
        }
        for (int idx = tid; idx < D_SZ * 28; idx += 512)   // finite K-pad c in [100,128)
            xeT[xet_off(idx / 28, C_SZ + (idx % 28))] = 0;
    }

    // ---- consume prologue prefetch: pack + swizzled ds_write of prev(0) ----
    {
        uint4 u;
        int idx, row, q;
        u.x = packhl(pf0.x); u.y = packhl(pf0.y); u.z = packhl(pf0.z); u.w = packhl(pf0.w);
        idx = tid;        row = idx / 48; q = idx % 48;
        *(uint4*)(ylds + row * 192 + ((q ^ (row & 7)) << 2)) = u;
        u.x = packhl(pf1.x); u.y = packhl(pf1.y); u.z = packhl(pf1.z); u.w = packhl(pf1.w);
        idx = tid + 512;  row = idx / 48; q = idx % 48;
        *(uint4*)(ylds + row * 192 + ((q ^ (row & 7)) << 2)) = u;
        u.x = packhl(pf2.x); u.y = packhl(pf2.y); u.z = packhl(pf2.z); u.w = packhl(pf2.w);
        idx = tid + 1024; row = idx / 48; q = idx % 48;
        *(uint4*)(ylds + row * 192 + ((q ^ (row & 7)) << 2)) = u;
    }
    __syncthreads();   // B_a: xeT + prev(0) ready

    for (int chunk = 0; chunk < NCH; ++chunk) {
        const int pbase = chunk * CH;
        const int pr0 = 16 * wm + 4 * lg;

        // ---- early: cpc values for this wave's outputs (consumed at exp) ----
        float cpcv[2][4];
        #pragma unroll
        for (int nt = 0; nt < 2; ++nt)
            #pragma unroll
            for (int r2 = 0; r2 < 4; ++r2)
                cpcv[nt][r2] = cpc[(pbase + pr0 + r2) * 128 + 32 * wn + 16 * nt + l15];

        // ---- issue prev(chunk+1) prefetch (hides under G2'+softmax+G3) ----
        float4 pf0n, pf1n, pf2n;
        if (chunk + 1 < NCH) {
            const float* pc = prev + (bP + (size_t)(chunk + 1) * CH) * D_SZ;
            pf0n = *(const float4*)(pc + (tid)        * 4);
            pf1n = *(const float4*)(pc + (tid + 512)  * 4);
            pf2n = *(const float4*)(pc + (tid + 1024) * 4);
        }

        // ---- G2': s[32][128] = prev @ W2C^T, hi/lo split, 2-deep pipelined ----
        f32x4 sacc[2] = {fzero, fzero};
        {
            const int prow = 16 * wm + l15;
            const int r7 = prow & 7;
            const uint_t* abase = ylds + prow * 192;
            bf16x8 bh[2][2], bl[2][2];
            uint4 au[2][2];
            {   // preload kt = 0
                const int q0 = lg * 2;
                au[0][0] = *(const uint4*)(abase + ((q0 ^ r7) << 2));
                au[0][1] = *(const uint4*)(abase + (((q0 + 1) ^ r7) << 2));
                #pragma unroll
                for (int nt = 0; nt < 2; ++nt) {
                    const int crow = 32 * wn + 16 * nt + l15;
                    bh[0][nt] = *(const bf16x8*)(wc_hi + crow * D_SZ + koff);
                    bl[0][nt] = *(const bf16x8*)(wc_lo + crow * D_SZ + koff);
                }
            }
            #pragma unroll
            for (int kt = 0; kt < 6; ++kt) {
                const int cur = kt & 1, nxt = cur ^ 1;
                if (kt < 5) {   // prefetch kt+1
                    const int q1 = (kt + 1) * 8 + lg * 2;
                    au[nxt][0] = *(const uint4*)(abase + ((q1 ^ r7) << 2));
                    au[nxt][1] = *(const uint4*)(abase + (((q1 + 1) ^ r7) << 2));
                    const int e1 = (kt + 1) * 32 + koff;
                    #pragma unroll
                    for (int nt = 0; nt < 2; ++nt) {
                        const int crow = 32 * wn + 16 * nt + l15;
                        bh[nxt][nt] = *(const bf16x8*)(wc_hi + crow * D_SZ + e1);
                        bl[nxt][nt] = *(const bf16x8*)(wc_lo + crow * D_SZ + e1);
                    }
                }
                const uint_t uu[8] = {au[cur][0].x, au[cur][0].y, au[cur][0].z, au[cur][0].w,
                                      au[cur][1].x, au[cur][1].y, au[cur][1].z, au[cur][1].w};
                bf16x8 ah, al;
                #pragma unroll
                for (int j = 0; j < 8; ++j) {
                    ah[j] = (short)(uu[j] >> 16);
                    al[j] = (short)(uu[j] & 0xffffu);
                }
                #pragma unroll
                for (int nt = 0; nt < 2; ++nt) {
                    sacc[nt] = MFMA16(ah, bh[cur][nt], sacc[nt], 0, 0, 0);
                    sacc[nt] = MFMA16(al, bh[cur][nt], sacc[nt], 0, 0, 0);
                    sacc[nt] = MFMA16(ah, bl[cur][nt], sacc[nt], 0, 0, 0);
                }
            }
        }

        // ---- max-free softmax: exp in reg, partials -> xeT pad (finite bf16 hi/lo) ----
        float e[2][4];
        {
            #pragma unroll
            for (int nt = 0; nt < 2; ++nt) {
                const int col = 32 * wn + 16 * nt + l15;
                #pragma unroll
                for (int r2 = 0; r2 < 4; ++r2)
                    e[nt][r2] = (col < C_SZ) ? __expf(sacc[nt][r2] + cpcv[nt][r2]) : 0.f;
            }
            #pragma unroll
            for (int r2 = 0; r2 < 4; ++r2) {
                float rs = e[0][r2] + e[1][r2];
                rs += __shfl_xor(rs, 1); rs += __shfl_xor(rs, 2);
                rs += __shfl_xor(rs, 4); rs += __shfl_xor(rs, 8);
                if (l15 == 0) {
                    const int dd = pr0 + r2;   // row in [0,32)
                    // slot: logical quad 14 (cols 112..119, mask=0) of xeT row dd
                    xeT32[dd * 64 + ((14 ^ (dd & 7)) << 2) + wn] = packhl(rs);
                }
            }
        }
        __syncthreads();   // B4: psum ready AND all prev reads done (maskb writeable)

        // ---- finalize: combine 4 partials, write maskb (cols>=100 stay 0) ----
        {
            #pragma unroll
            for (int r2 = 0; r2 < 4; ++r2) {
                const int dd = pr0 + r2;
                const uint4 ps = *(const uint4*)(xeT32 + dd * 64 + ((14 ^ (dd & 7)) << 2));
                const float sum = (b2f((ushort_t)(ps.x >> 16)) + b2f((ushort_t)(ps.x & 0xffffu)))
                                + (b2f((ushort_t)(ps.y >> 16)) + b2f((ushort_t)(ps.y & 0xffffu)))
                                + (b2f((ushort_t)(ps.z >> 16)) + b2f((ushort_t)(ps.z & 0xffffu)))
                                + (b2f((ushort_t)(ps.w >> 16)) + b2f((ushort_t)(ps.w & 0xffffu)));
                const float inv = 1.f / sum;
                #pragma unroll
                for (int nt = 0; nt < 2; ++nt) {
                    const int col = 32 * wn + 16 * nt + l15;
                    maskb[dd * 128 + ((((col >> 3) ^ (dd & 7)) << 3) | (col & 7))]
                        = f2b(e[nt][r2] * inv);
                }
            }
        }
        __syncthreads();   // B5: maskb ready

        // ---- G3: agg[32][192] = mask @ x_emb (K=128 padded), + epilogue store ----
        {
            f32x4 acc[3] = {fzero, fzero, fzero};
            const int arow = 16 * wm + l15;
            #pragma unroll
            for (int kt = 0; kt < 4; ++kt) {
                const int c0 = kt * 32 + koff;
                const bf16x8 a = *(const bf16x8*)(maskb + arow * 128 +
                                                  (((c0 >> 3) ^ (arow & 7)) << 3));
                #pragma unroll
                for (int nt = 0; nt < 3; ++nt) {
                    const int d = 48 * wn + 16 * nt + l15;
                    const bf16x8 bx = *(const bf16x8*)(xeT + d * 128 +
                                                       (((c0 >> 3) ^ (d & 7)) << 3));
                    acc[nt] = MFMA16(a, bx, acc[nt], 0, 0, 0);
                }
            }
            const int prr = pbase + 16 * wm + 4 * lg;
            #pragma unroll
            for (int r2 = 0; r2 < 4; ++r2) {
                const int p = prr + r2;
                const float sc = 1.f + wexp[p];
                const float bi = bexp[p];
                float* orow = out + (bP + p) * D_SZ;
                #pragma unroll
                for (int nt = 0; nt < 3; ++nt) {
                    const int d = 48 * wn + 16 * nt + l15;
                    orow[d] = fmaf(acc[nt][r2], sc, bi);
                }
            }
        }
        __syncthreads();   // B6: maskb reads done -> ylds reusable

        // ---- consume prefetch: pack + ds_write prev(chunk+1) ----
        if (chunk + 1 < NCH) {
            uint4 u;
            int idx, row, q;
            u.x = packhl(pf0n.x); u.y = packhl(pf0n.y); u.z = packhl(pf0n.z); u.w = packhl(pf0n.w);
            idx = tid;        row = idx / 48; q = idx % 48;
            *(uint4*)(ylds + row * 192 + ((q ^ (row & 7)) << 2)) = u;
            u.x = packhl(pf1n.x); u.y = packhl(pf1n.y); u.z = packhl(pf1n.z); u.w = packhl(pf1n.w);
            idx = tid + 512;  row = idx / 48; q = idx % 48;
            *(uint4*)(ylds + row * 192 + ((q ^ (row & 7)) << 2)) = u;
            u.x = packhl(pf2n.x); u.y = packhl(pf2n.y); u.z = packhl(pf2n.z); u.w = packhl(pf2n.w);
            idx = tid + 1024; row = idx / 48; q = idx % 48;
            *(uint4*)(ylds + row * 192 + ((q ^ (row & 7)) << 2)) = u;
            __syncthreads();   // B_a: prev(chunk+1) ready
        }
    }
}

extern "C" void kernel_launch(void* const* d_in, const int* in_sizes, int n_in,
                              void* d_out, int out_size, void* d_ws, size_t ws_size,
                              hipStream_t stream) {
    const float* x           = (const float*)d_in[0];
    const float* prev        = (const float*)d_in[1];
    const float* wfe         = (const float*)d_in[2];
    const float* bfe         = (const float*)d_in[3];
    const float* ln_emb_w    = (const float*)d_in[4];
    const float* ln_emb_b    = (const float*)d_in[5];
    const float* ln_col_w    = (const float*)d_in[6];
    const float* ln_col_b    = (const float*)d_in[7];
    const float* ln_prompt_w = (const float*)d_in[8];
    const float* ln_prompt_b = (const float*)d_in[9];
    const float* W_imp       = (const float*)d_in[10];
    const float* b_imp       = (const float*)d_in[11];
    const float* emb_column  = (const float*)d_in[12];
    const float* emb_prompt  = (const float*)d_in[13];
    const float* wexp        = (const float*)d_in[14];
    const float* bexp        = (const float*)d_in[15];
    float* out = (float*)d_out;

    // ws layout (163840 B total; original session kernel proved ws_size >= 175104)
    char* ws = (char*)d_ws;
    ushort_t* wc_hi = (ushort_t*)(ws + 0);       // 49152 B
    ushort_t* wc_lo = (ushort_t*)(ws + 49152);   // 49152 B
    float*    cpc   = (float*)(ws + 98304);      // 65536 B

    precompute1<<<2 * P_SZ, 192, 0, stream>>>(emb_column, emb_prompt,
        ln_col_w, ln_col_b, ln_prompt_w, ln_prompt_b, W_imp, b_imp, wc_hi, wc_lo);
    precompute2<<<P_SZ, 128, 0, stream>>>(emb_column, ln_col_w, ln_col_b, cpc);
    fused<<<B_SZ, 512, 0, stream>>>(x, prev, wfe, bfe, ln_emb_w, ln_emb_b,
        wexp, bexp, wc_hi, wc_lo, cpc, out);
}